// Round 2
// baseline (180.551 us; speedup 1.0000x reference)
//
#include <hip/hip_runtime.h>

// HolographicConv: out = Re(ifft2(fft2(x) * W)), B == C_out == 16 -> pure
// elementwise complex multiply in frequency space per (b,c) image slice.
// 256 images of 256x256 complex64.
//
// Axis-swapped pipeline; intermediate lives TRANSPOSED: wsT[v*256 + k].
//   K1: FFT over u (cols):  x rows coalesced -> LDS tile -> col FFT
//       -> write wsT[v][:] contiguous (coalesced, no out tile)
//   K2: FFT over v + mul W + IFFT over v, per 16-k stripe, IN-PLACE on wsT.
//       wsT rows give 128B coalesced tile loads; W(k,l) is read COALESCED
//       straight into registers (no W tile).
//   K3: IFFT over k: wsT rows fully contiguous (no in tile) -> transpose
//       tile (floats) -> coalesced out writes.
//
// FFT-256 = radix-4 Stockham, 4 stages, one wave per transform, 4 complex
// elems/lane (v[r] = elem(lane + 64*r) at every stage boundary). Each wave
// runs TWO interleaved FFTs (ILP-2) against two LDS scratch regions.

#define PI_F 3.14159265358979323846f

__device__ __forceinline__ float2 cadd(float2 a, float2 b){ return make_float2(a.x+b.x, a.y+b.y); }
__device__ __forceinline__ float2 csub(float2 a, float2 b){ return make_float2(a.x-b.x, a.y-b.y); }
__device__ __forceinline__ float2 cmul(float2 a, float2 b){
  return make_float2(a.x*b.x - a.y*b.y, a.x*b.y + a.y*b.x);
}

// XOR swizzle for the Stockham scratch.
__device__ __forceinline__ int SW(int e){ return e ^ (e >> 4); }

template<int DIR>  // +1: forward e^{-i}, -1: inverse e^{+i} (unnormalized)
__device__ __forceinline__ void bfly4(float2& a, float2& b, float2& c, float2& d,
                                      float2 w1, float2 w2, float2 w3)
{
  float2 apc = cadd(a,c), amc = csub(a,c);
  float2 bpd = cadd(b,d), bmd = csub(b,d);
  float2 jb = (DIR > 0) ? make_float2(-bmd.y, bmd.x)   //  i*(b-d)
                        : make_float2( bmd.y,-bmd.x);  // -i*(b-d)
  a = cadd(apc, bpd);
  b = cmul(w1, csub(amc, jb));
  c = cmul(w2, csub(apc, bpd));
  d = cmul(w3, cadd(amc, jb));
}

// Two interleaved FFT-256s per wave (independent LDS chains -> ILP-2).
template<int DIR>
__device__ __forceinline__ void fft256_x2(float2 va[4], float2 vb[4],
                                          float2* sa, float2* sb,
                                          const float2* tw, int lane)
{
  #pragma unroll
  for (int st = 0; st < 3; ++st) {               // s = 1, 4, 16
    const int s  = 1 << (2*st);
    const int ps = lane & ~(s-1);                // p*s
    const int q  = lane &  (s-1);
    float2 w1 = tw[ps];
    float2 w2 = tw[(2*ps) & 255];
    float2 w3 = tw[(3*ps) & 255];
    if (DIR < 0) { w1.y = -w1.y; w2.y = -w2.y; w3.y = -w3.y; }
    bfly4<DIR>(va[0], va[1], va[2], va[3], w1, w2, w3);
    bfly4<DIR>(vb[0], vb[1], vb[2], vb[3], w1, w2, w3);
    const int dbase = q + 4*ps;                  // q + s*4p
    __builtin_amdgcn_wave_barrier();
    sa[SW(dbase + 0*s)] = va[0];
    sb[SW(dbase + 0*s)] = vb[0];
    sa[SW(dbase + 1*s)] = va[1];
    sb[SW(dbase + 1*s)] = vb[1];
    sa[SW(dbase + 2*s)] = va[2];
    sb[SW(dbase + 2*s)] = vb[2];
    sa[SW(dbase + 3*s)] = va[3];
    sb[SW(dbase + 3*s)] = vb[3];
    __builtin_amdgcn_wave_barrier();             // in-order LDS per wave -> safe
    va[0] = sa[SW(lane +   0)];
    vb[0] = sb[SW(lane +   0)];
    va[1] = sa[SW(lane +  64)];
    vb[1] = sb[SW(lane +  64)];
    va[2] = sa[SW(lane + 128)];
    vb[2] = sb[SW(lane + 128)];
    va[3] = sa[SW(lane + 192)];
    vb[3] = sb[SW(lane + 192)];
    __builtin_amdgcn_wave_barrier();
  }
  const float2 one = make_float2(1.f, 0.f);      // s=64 stage: unit twiddles
  bfly4<DIR>(va[0], va[1], va[2], va[3], one, one, one);
  bfly4<DIR>(vb[0], vb[1], vb[2], vb[3], one, one, one);
}

__device__ __forceinline__ void init_tw(float2* tw, int tid)
{
  float sv, cv;
  sincosf(-2.0f * PI_F * (float)tid / 256.0f, &sv, &cv);
  tw[tid] = make_float2(cv, sv);
}

// ---------------- K1: FFT over u (columns), write wsT[v][k] ----------------
__global__ __launch_bounds__(256, 3) void k_colfft(const float* __restrict__ xr,
                                                   const float* __restrict__ xi,
                                                   float2* __restrict__ wsT)
{
  __shared__ float2 xt[256][17];        // (u, v_local)
  __shared__ float2 scr[4][2][256];
  __shared__ float2 tw[256];
  const int tid = threadIdx.x;
  init_tw(tw, tid);
  const int imgl = blockIdx.x >> 4;
  const int v0   = (blockIdx.x & 15) * 16;
  const size_t ib = (size_t)imgl * 65536;
  const int c  = tid & 15;
  const int h0 = tid >> 4;
  #pragma unroll
  for (int t = 0; t < 16; ++t) {
    const int u = t*16 + h0;
    xt[u][c] = make_float2(xr[ib + (size_t)u*256 + v0 + c],
                           xi[ib + (size_t)u*256 + v0 + c]);
  }
  __syncthreads();
  const int wave = tid >> 6, lane = tid & 63;
  #pragma unroll 1
  for (int cc = 0; cc < 2; ++cc) {
    const int colA = wave*4 + cc*2, colB = colA + 1;
    float2 va[4], vb[4];
    #pragma unroll
    for (int r = 0; r < 4; ++r) { va[r] = xt[lane + 64*r][colA];
                                  vb[r] = xt[lane + 64*r][colB]; }
    fft256_x2<1>(va, vb, scr[wave][0], scr[wave][1], tw, lane);
    float2* oA = wsT + ib + (size_t)(v0 + colA)*256;
    float2* oB = wsT + ib + (size_t)(v0 + colB)*256;
    #pragma unroll
    for (int r = 0; r < 4; ++r) { oA[lane + 64*r] = va[r];
                                  oB[lane + 64*r] = vb[r]; }
  }
}

// ---------------- K2: FFT over v, * W, IFFT over v (in-place on wsT) -------
__global__ __launch_bounds__(256, 3) void k_rowpass(float2* __restrict__ wsT,
                                                    const float* __restrict__ wr,
                                                    const float* __restrict__ wi,
                                                    int img0)
{
  __shared__ float2 xt[256][17];        // (v, k_local)
  __shared__ float2 scr[4][2][256];
  __shared__ float2 tw[256];
  const int tid = threadIdx.x;
  init_tw(tw, tid);
  const int imgl = blockIdx.x >> 4;
  const int k0   = (blockIdx.x & 15) * 16;
  const size_t ib = (size_t)imgl * 65536;
  const size_t wb = (size_t)(img0 + imgl) * 65536;
  const int c  = tid & 15;
  const int h0 = tid >> 4;
  #pragma unroll
  for (int t = 0; t < 16; ++t) {
    const int v = t*16 + h0;
    xt[v][c] = wsT[ib + (size_t)v*256 + k0 + c];
  }
  __syncthreads();
  const int wave = tid >> 6, lane = tid & 63;
  #pragma unroll 1
  for (int cc = 0; cc < 2; ++cc) {
    const int colA = wave*4 + cc*2, colB = colA + 1;
    float2 va[4], vb[4];
    #pragma unroll
    for (int r = 0; r < 4; ++r) { va[r] = xt[lane + 64*r][colA];
                                  vb[r] = xt[lane + 64*r][colB]; }
    fft256_x2<1>(va, vb, scr[wave][0], scr[wave][1], tw, lane);
    // W(k, l): k fixed per column, l = lane + 64r -> fully coalesced loads.
    const float* wrA = wr + wb + (size_t)(k0 + colA)*256;
    const float* wiA = wi + wb + (size_t)(k0 + colA)*256;
    const float* wrB = wr + wb + (size_t)(k0 + colB)*256;
    const float* wiB = wi + wb + (size_t)(k0 + colB)*256;
    #pragma unroll
    for (int r = 0; r < 4; ++r) {
      const int l = lane + 64*r;
      va[r] = cmul(va[r], make_float2(wrA[l], wiA[l]));
      vb[r] = cmul(vb[r], make_float2(wrB[l], wiB[l]));
    }
    fft256_x2<-1>(va, vb, scr[wave][0], scr[wave][1], tw, lane);
    #pragma unroll
    for (int r = 0; r < 4; ++r) { xt[lane + 64*r][colA] = va[r];   // own cols only
                                  xt[lane + 64*r][colB] = vb[r]; }
  }
  __syncthreads();
  #pragma unroll
  for (int t = 0; t < 16; ++t) {
    const int v = t*16 + h0;
    wsT[ib + (size_t)v*256 + k0 + c] = xt[v][c];   // exactly the cells we read
  }
}

// ---------------- K3: IFFT over k, write Re/65536 (transposed out) ---------
__global__ __launch_bounds__(256, 3) void k_rowifft(const float2* __restrict__ wsT,
                                                    float* __restrict__ out)
{
  __shared__ float ot[256][17];         // (u, v_local) real only
  __shared__ float2 scr[4][2][256];
  __shared__ float2 tw[256];
  const int tid = threadIdx.x;
  init_tw(tw, tid);
  __syncthreads();                      // tw ready (no other pre-pass here)
  const int imgl = blockIdx.x >> 4;
  const int v0   = (blockIdx.x & 15) * 16;
  const size_t ib = (size_t)imgl * 65536;
  const int wave = tid >> 6, lane = tid & 63;
  const float sc = 1.0f / 65536.0f;     // full ifft2 normalization
  #pragma unroll 1
  for (int cc = 0; cc < 2; ++cc) {
    const int colA = wave*4 + cc*2, colB = colA + 1;
    const float2* pA = wsT + ib + (size_t)(v0 + colA)*256;
    const float2* pB = wsT + ib + (size_t)(v0 + colB)*256;
    float2 va[4], vb[4];
    #pragma unroll
    for (int r = 0; r < 4; ++r) { va[r] = pA[lane + 64*r];
                                  vb[r] = pB[lane + 64*r]; }
    fft256_x2<-1>(va, vb, scr[wave][0], scr[wave][1], tw, lane);
    #pragma unroll
    for (int r = 0; r < 4; ++r) { ot[lane + 64*r][colA] = va[r].x * sc;
                                  ot[lane + 64*r][colB] = vb[r].x * sc; }
  }
  __syncthreads();
  const int c  = tid & 15;
  const int h0 = tid >> 4;
  #pragma unroll
  for (int t = 0; t < 16; ++t) {
    const int u = t*16 + h0;
    out[ib + (size_t)u*256 + v0 + c] = ot[u][c];
  }
}

extern "C" void kernel_launch(void* const* d_in, const int* in_sizes, int n_in,
                              void* d_out, int out_size, void* d_ws, size_t ws_size,
                              hipStream_t stream)
{
  const float* xr = (const float*)d_in[0];
  const float* xi = (const float*)d_in[1];
  const float* wr = (const float*)d_in[2];
  const float* wi = (const float*)d_in[3];
  float* out = (float*)d_out;

  const int IMG = 256;                                    // B * C_IN
  const size_t per_img = (size_t)65536 * sizeof(float2);  // 512 KiB
  int ipc = (int)(ws_size / per_img);                     // images per chunk
  if (ipc < 1)   ipc = 1;
  if (ipc > IMG) ipc = IMG;
  float2* wsp = (float2*)d_ws;

  for (int img0 = 0; img0 < IMG; img0 += ipc) {
    const int n = (IMG - img0 < ipc) ? (IMG - img0) : ipc;
    k_colfft <<<dim3(n*16), dim3(256), 0, stream>>>(xr + (size_t)img0*65536,
                                                    xi + (size_t)img0*65536, wsp);
    k_rowpass<<<dim3(n*16), dim3(256), 0, stream>>>(wsp, wr, wi, img0);
    k_rowifft<<<dim3(n*16), dim3(256), 0, stream>>>(wsp, out + (size_t)img0*65536);
  }
}